// Round 19
// baseline (331.078 us; speedup 1.0000x reference)
//
#include <hip/hip_runtime.h>
#include <cstdint>

#define NQ 4096
#define NKTOT 16448
#define CDIM 256
#define FF 2048
#define FSPLIT 16

typedef unsigned short u16;
typedef __attribute__((ext_vector_type(8))) short short8;
typedef __attribute__((ext_vector_type(4))) float f32x4;

#define GLOAD16(gp, lp) __builtin_amdgcn_global_load_lds( \
    (const __attribute__((address_space(1))) unsigned int*)(gp), \
    (__attribute__((address_space(3))) unsigned int*)(lp), 16, 0, 0)

#if __has_builtin(__builtin_amdgcn_exp2f)
#define EXP2(x) __builtin_amdgcn_exp2f(x)
#else
#define EXP2(x) exp2f(x)
#endif

static __device__ __forceinline__ u16 f2b(float f) {
  union { float f; unsigned u; } v; v.f = f;
  unsigned r = v.u + 0x7fffu + ((v.u >> 16) & 1u);
  return (u16)(r >> 16);
}
static __device__ __forceinline__ float b2f(u16 h) {
  union { unsigned u; float f; } v; v.u = ((unsigned)h) << 16; return v.f;
}

// pack 8 f32 -> 8 bf16 via 4x v_cvt_pk_bf16_f32 (HW RTNE)
static __device__ __forceinline__ short8 pack8(float a0, float a1, float a2, float a3,
                                               float b0, float b1, float b2, float b3) {
  union { unsigned u[4]; short8 v; } r;
  asm("v_cvt_pk_bf16_f32 %0, %1, %2" : "=v"(r.u[0]) : "v"(a0), "v"(a1));
  asm("v_cvt_pk_bf16_f32 %0, %1, %2" : "=v"(r.u[1]) : "v"(a2), "v"(a3));
  asm("v_cvt_pk_bf16_f32 %0, %1, %2" : "=v"(r.u[2]) : "v"(b0), "v"(b1));
  asm("v_cvt_pk_bf16_f32 %0, %1, %2" : "=v"(r.u[3]) : "v"(b2), "v"(b3));
  return r.v;
}

static __device__ __forceinline__ f32x4 mfma16(short8 a, short8 b, f32x4 c) {
  return __builtin_amdgcn_mfma_f32_16x16x32_bf16(a, b, c, 0, 0, 0);
}

// ---------------- elementwise kernels ----------------

struct CvtBatch {
  const float* src[12];
  u16* dst[12];
  int n4[12];
};

__global__ void k_f2b_batch(CvtBatch cb) {
  int b = blockIdx.y;
  const float* in = cb.src[b];
  u16* out = cb.dst[b];
  int n4 = cb.n4[b];
  int stride = gridDim.x * blockDim.x;
  for (int i = blockIdx.x * blockDim.x + threadIdx.x; i < n4; i += stride) {
    float4 v = ((const float4*)in)[i];
    ushort4 o;
    o.x = f2b(v.x); o.y = f2b(v.y); o.z = f2b(v.z); o.w = f2b(v.w);
    ((ushort4*)out)[i] = o;
  }
}

// image: one read -> bf16 img16 + f32 passthrough out_img
__global__ void k_cvtcopy(const float* __restrict__ in, u16* __restrict__ ob,
                          float* __restrict__ of, int n4) {
  int stride = gridDim.x * blockDim.x;
  for (int i = blockIdx.x * blockDim.x + threadIdx.x; i < n4; i += stride) {
    float4 v = ((const float4*)in)[i];
    ushort4 o;
    o.x = f2b(v.x); o.y = f2b(v.y); o.z = f2b(v.z); o.w = f2b(v.w);
    ((ushort4*)ob)[i] = o;
    ((float4*)of)[i] = v;
  }
}

__global__ void k_cat3(const float* __restrict__ a, const float* __restrict__ b,
                       const float* __restrict__ c, float* __restrict__ o) {
  int i = threadIdx.x;
  o[i] = (i < 256) ? a[i] : ((i < 512) ? b[i - 256] : c[i - 512]);
}

__global__ __launch_bounds__(256)
void k_ln(const float* __restrict__ x, const float* __restrict__ w,
          const float* __restrict__ b, u16* __restrict__ out, int M) {
  int row = blockIdx.x * 4 + (threadIdx.x >> 6);
  int lane = threadIdx.x & 63;
  const float4 v = ((const float4*)(x + (size_t)row * CDIM))[lane];
  float s = v.x + v.y + v.z + v.w;
  float s2 = v.x * v.x + v.y * v.y + v.z * v.z + v.w * v.w;
  #pragma unroll
  for (int d = 1; d < 64; d <<= 1) { s += __shfl_xor(s, d); s2 += __shfl_xor(s2, d); }
  float mean = s * (1.0f / CDIM);
  float rstd = rsqrtf(s2 * (1.0f / CDIM) - mean * mean + 1e-5f);
  float4 wv = ((const float4*)w)[lane];
  float4 bv = ((const float4*)b)[lane];
  ushort4 o;
  o.x = f2b((v.x - mean) * rstd * wv.x + bv.x);
  o.y = f2b((v.y - mean) * rstd * wv.y + bv.y);
  o.z = f2b((v.z - mean) * rstd * wv.z + bv.z);
  o.w = f2b((v.w - mean) * rstd * wv.w + bv.w);
  ((ushort4*)(out + (size_t)row * CDIM))[lane] = o;
}

// ---------------- GEMM: 64x64 tile, BK=64, fragment-order DMA, double-buffered ----

template<int GELU, int HASADD, int OUTBF, int HASBIAS>
__global__ __launch_bounds__(256)
void k_gemm(const u16* __restrict__ A, const u16* __restrict__ W,
            const float* __restrict__ bias, const float* __restrict__ Cadd,
            void* __restrict__ outp, int M, int N, int K, int lda) {
  __shared__ u16 Sg[2][2][4096];
  const int bm = blockIdx.y * 64, bn = blockIdx.x * 64;
  const int tid = threadIdx.x;
  const int lane = tid & 63, wid = tid >> 6;
  const int r16 = lane & 15, g = lane >> 4;
  const int wm = (wid >> 1) * 32, wn = (wid & 1) * 32;
  f32x4 acc[2][2];
  #pragma unroll
  for (int i = 0; i < 2; ++i)
    #pragma unroll
    for (int j = 0; j < 2; ++j)
      #pragma unroll
      for (int r = 0; r < 4; ++r) acc[i][j][r] = 0.0f;
  const int ca0 = (wid >> 1) * 4, cb0 = (wid & 1) * 4;

  #define GSTAGE(k0s, nb) { \
    _Pragma("unroll") \
    for (int j = 0; j < 4; ++j) { \
      const int c = wid * 4 + j; \
      const int cc = c & 7; \
      const u16* base = (c < 8) ? A : W; \
      const int row = ((c < 8) ? bm : bn) + (cc >> 1) * 16 + r16; \
      const int col = (k0s) + (cc & 1) * 32 + g * 8; \
      GLOAD16(base + (size_t)row * lda + col, &Sg[nb][c >> 3][cc * 512]); \
    } }

  GSTAGE(0, 0);
  __syncthreads();
  int buf = 0;
  for (int k0 = 0; k0 < K; k0 += 64, buf ^= 1) {
    if (k0 + 64 < K) GSTAGE(k0 + 64, buf ^ 1);
    #pragma unroll
    for (int kc = 0; kc < 2; ++kc) {
      short8 a0 = *(const short8*)(&Sg[buf][0][(ca0 + kc) * 512 + lane * 8]);
      short8 a1 = *(const short8*)(&Sg[buf][0][(ca0 + 2 + kc) * 512 + lane * 8]);
      short8 b0 = *(const short8*)(&Sg[buf][1][(cb0 + kc) * 512 + lane * 8]);
      short8 b1 = *(const short8*)(&Sg[buf][1][(cb0 + 2 + kc) * 512 + lane * 8]);
      acc[0][0] = mfma16(a0, b0, acc[0][0]);
      acc[0][1] = mfma16(a0, b1, acc[0][1]);
      acc[1][0] = mfma16(a1, b0, acc[1][0]);
      acc[1][1] = mfma16(a1, b1, acc[1][1]);
    }
    __syncthreads();
  }
  #pragma unroll
  for (int tr = 0; tr < 2; ++tr)
    #pragma unroll
    for (int tc = 0; tc < 2; ++tc)
      #pragma unroll
      for (int r = 0; r < 4; ++r) {
        int row = bm + wm + tr * 16 + g * 4 + r;
        int col = bn + wn + tc * 16 + r16;
        float v = acc[tr][tc][r];
        if (HASBIAS) v += bias[col];
        if (HASADD) v += Cadd[(size_t)row * N + col];
        if (GELU) v = 0.5f * v * (1.0f + erff(v * 0.70710678118654752f));
        if (OUTBF) ((u16*)outp)[(size_t)row * N + col] = f2b(v);
        else ((float*)outp)[(size_t)row * N + col] = v;
      }
}

// fused SA qkv GEMM: N=768, K=256 (64x64 tile). Epilogue: rope/scale/convert.
__global__ __launch_bounds__(256)
void k_gemm_qkv(const u16* __restrict__ A, const u16* __restrict__ W,
                const float* __restrict__ bias, const float* __restrict__ freqs,
                u16* __restrict__ qr, u16* __restrict__ kr, u16* __restrict__ vb,
                float qscl) {
  __shared__ u16 Sg[2][2][4096];
  const int bm = blockIdx.y * 64, bn = blockIdx.x * 64;
  const int tid = threadIdx.x;
  const int lane = tid & 63, wid = tid >> 6;
  const int r16 = lane & 15, g = lane >> 4;
  const int wm = (wid >> 1) * 32, wn = (wid & 1) * 32;
  const int lda = 256;
  const u16* Wb = W;
  #define AW(c) ((c) < 8 ? A : Wb)
  f32x4 acc[2][2];
  #pragma unroll
  for (int i = 0; i < 2; ++i)
    #pragma unroll
    for (int j = 0; j < 2; ++j)
      #pragma unroll
      for (int r = 0; r < 4; ++r) acc[i][j][r] = 0.0f;
  const int ca0 = (wid >> 1) * 4, cb0 = (wid & 1) * 4;

  #define GSTAGEQ(k0s, nb) { \
    _Pragma("unroll") \
    for (int j = 0; j < 4; ++j) { \
      const int c = wid * 4 + j; \
      const int cc = c & 7; \
      const u16* base = AW(c); \
      const int row = ((c < 8) ? bm : bn) + (cc >> 1) * 16 + r16; \
      const int col = (k0s) + (cc & 1) * 32 + g * 8; \
      GLOAD16(base + (size_t)row * lda + col, &Sg[nb][c >> 3][cc * 512]); \
    } }

  GSTAGEQ(0, 0);
  __syncthreads();
  int buf = 0;
  for (int k0 = 0; k0 < 256; k0 += 64, buf ^= 1) {
    if (k0 + 64 < 256) GSTAGEQ(k0 + 64, buf ^ 1);
    #pragma unroll
    for (int kc = 0; kc < 2; ++kc) {
      short8 a0 = *(const short8*)(&Sg[buf][0][(ca0 + kc) * 512 + lane * 8]);
      short8 a1 = *(const short8*)(&Sg[buf][0][(ca0 + 2 + kc) * 512 + lane * 8]);
      short8 b0 = *(const short8*)(&Sg[buf][1][(cb0 + kc) * 512 + lane * 8]);
      short8 b1 = *(const short8*)(&Sg[buf][1][(cb0 + 2 + kc) * 512 + lane * 8]);
      acc[0][0] = mfma16(a0, b0, acc[0][0]);
      acc[0][1] = mfma16(a0, b1, acc[0][1]);
      acc[1][0] = mfma16(a1, b0, acc[1][0]);
      acc[1][1] = mfma16(a1, b1, acc[1][1]);
    }
    __syncthreads();
  }
  #pragma unroll
  for (int tr = 0; tr < 2; ++tr)
    #pragma unroll
    for (int tc = 0; tc < 2; ++tc)
      #pragma unroll
      for (int r = 0; r < 4; ++r) {
        int row = bm + wm + tr * 16 + g * 4 + r;
        int col = bn + wn + tc * 16 + r16;
        float v = acc[tr][tc][r] + bias[col];
        int sec = col >> 8;         // 0=q 1=k 2=v
        int c = col & 255;
        float vp = __shfl_xor(v, 1);
        if (sec < 2) {
          float4 f = ((const float4*)freqs)[(size_t)row * 128 + (c >> 1)];
          v = (c & 1) ? (f.z * vp + f.w * v) : (f.x * v + f.y * vp);
          if (sec == 0) v *= qscl;
        }
        u16* ob = (sec == 0) ? qr : ((sec == 1) ? kr : vb);
        ob[(size_t)row * 256 + c] = f2b(v);
      }
}

// ---- batched CA GEMMs: 3 independent N=256 ops in one dispatch, fused rope ----
struct GOp {
  const u16 *A1, *W1, *A2, *W2;
  const float *b1, *b2, *cadd;
  u16* out;
  const float* freqs;   // null = no rope
  const int* nkxp;
  int limit_base;
  float scale;
};
struct GBatch { GOp op[3]; int start1, start2; };

__global__ __launch_bounds__(256)
void k_gemm_ca(GBatch gb) {
  __shared__ u16 Sg[2][2][4096];
  const int flat = blockIdx.x;
  const int oi = (flat >= gb.start1) + (flat >= gb.start2);
  const int local = flat - (oi == 0 ? 0 : (oi == 1 ? gb.start1 : gb.start2));
  const GOp op = gb.op[oi];
  const int bn = (local & 3) * 64;
  const int bm = (local >> 2) * 64;
  const int K = op.A2 ? 512 : 256;
  const int tid = threadIdx.x;
  const int lane = tid & 63, wid = tid >> 6;
  const int r16 = lane & 15, g = lane >> 4;
  const int wm = (wid >> 1) * 32, wn = (wid & 1) * 32;
  f32x4 acc[2][2];
  #pragma unroll
  for (int i = 0; i < 2; ++i)
    #pragma unroll
    for (int j = 0; j < 2; ++j)
      #pragma unroll
      for (int r = 0; r < 4; ++r) acc[i][j][r] = 0.0f;
  const int ca0 = (wid >> 1) * 4, cb0 = (wid & 1) * 4;

  #define GSTAGE_CA(k0s, nb) { \
    const u16* As = ((k0s) < 256) ? op.A1 : op.A2; \
    const u16* Ws = ((k0s) < 256) ? op.W1 : op.W2; \
    const int kk = (k0s) & 255; \
    _Pragma("unroll") \
    for (int j = 0; j < 4; ++j) { \
      const int c = wid * 4 + j; \
      const int cc = c & 7; \
      const u16* base = (c < 8) ? As : Ws; \
      const int row = ((c < 8) ? bm : bn) + (cc >> 1) * 16 + r16; \
      const int col = kk + (cc & 1) * 32 + g * 8; \
      GLOAD16(base + (size_t)row * 256 + col, &Sg[nb][c >> 3][cc * 512]); \
    } }

  GSTAGE_CA(0, 0);
  __syncthreads();
  int buf = 0;
  for (int k0 = 0; k0 < K; k0 += 64, buf ^= 1) {
    if (k0 + 64 < K) GSTAGE_CA(k0 + 64, buf ^ 1);
    #pragma unroll
    for (int kc = 0; kc < 2; ++kc) {
      short8 a0 = *(const short8*)(&Sg[buf][0][(ca0 + kc) * 512 + lane * 8]);
      short8 a1 = *(const short8*)(&Sg[buf][0][(ca0 + 2 + kc) * 512 + lane * 8]);
      short8 b0 = *(const short8*)(&Sg[buf][1][(cb0 + kc) * 512 + lane * 8]);
      short8 b1 = *(const short8*)(&Sg[buf][1][(cb0 + 2 + kc) * 512 + lane * 8]);
      acc[0][0] = mfma16(a0, b0, acc[0][0]);
      acc[0][1] = mfma16(a0, b1, acc[0][1]);
      acc[1][0] = mfma16(a1, b0, acc[1][0]);
      acc[1][1] = mfma16(a1, b1, acc[1][1]);
    }
    __syncthreads();
  }
  const int lim = op.limit_base - (op.nkxp ? *op.nkxp : 0);
  #pragma unroll
  for (int tr = 0; tr < 2; ++tr)
    #pragma unroll
    for (int tc = 0; tc < 2; ++tc)
      #pragma unroll
      for (int r = 0; r < 4; ++r) {
        int row = bm + wm + tr * 16 + g * 4 + r;
        int col = bn + wn + tc * 16 + r16;
        float v = acc[tr][tc][r] + op.b1[col];
        if (op.b2) v += op.b2[col];
        if (op.cadd) v += op.cadd[(size_t)row * 256 + col];
        if (op.freqs) {
          float vp = __shfl_xor(v, 1);
          if (row < lim) {
            float4 f = ((const float4*)op.freqs)[((size_t)(row & 4095)) * 128 + (col >> 1)];
            v = (col & 1) ? (f.z * vp + f.w * v) : (f.x * v + f.y * vp);
          }
          v *= op.scale;
        }
        op.out[(size_t)row * 256 + col] = f2b(v);
      }
}

// ---------------- flash attention (1 head, hd=256), KV-split partials ----------------
// 1D grid 512 with XCD-aware decode: s = (flat&7) + 8*(flat>>8), qb = (flat>>3)&31.
// All 32 q-blocks sharing a KV-split s land on one XCD -> s-slice of K/V stays
// L2-resident (FETCH 69.7 -> 19 MB measured). block 256 = 4 waves; wave owns
// 32 q-rows (2 subtiles); KV tile = 32 keys. Swapped QK^T natural key order;
// P packs into K=32 B-frag; PV = 1 mfma16 per dim-tile per q-subtile.
// K and V double-buffered, ONE barrier per tile.

#define FM2 23.0831206542f   // 16 * log2(e)

__global__ __launch_bounds__(256, 2)
void k_flash(const u16* __restrict__ Q, const u16* __restrict__ Kb, const u16* __restrict__ Vb,
             u16* __restrict__ Opart, float* __restrict__ lpart, int NT, int SPLIT) {
  __shared__ u16 Kf[2][8192];
  __shared__ u16 Vf[2][8192];
  const int flat = blockIdx.x;
  const int s = (flat & 7) + 8 * (flat >> 8);
  const int qb = (flat >> 3) & 31;
  const int tid = threadIdx.x, lane = tid & 63, wid = tid >> 6;
  const int r16 = lane & 15, g = lane >> 4;

  short8 qf[2][8];
  #pragma unroll
  for (int qs = 0; qs < 2; ++qs) {
    const size_t qrow = (size_t)qb * 128 + wid * 32 + qs * 16 + r16;
    #pragma unroll
    for (int kc = 0; kc < 8; ++kc)
      qf[qs][kc] = *(const short8*)(Q + qrow * CDIM + kc * 32 + g * 8);
  }

  float l_lane[2] = {0.0f, 0.0f};
  f32x4 oacc[2][16];
  #pragma unroll
  for (int qs = 0; qs < 2; ++qs)
    #pragma unroll
    for (int i = 0; i < 16; ++i)
      #pragma unroll
      for (int r = 0; r < 4; ++r) oacc[qs][i][r] = 0.0f;

  const int kp = tid & 15, dc = tid >> 4;
  const unsigned gw = ((unsigned)kp & 7u) >> 1;
  const unsigned mw = (gw + 2u * (unsigned)dc) & 7u;
  const unsigned wbase = (unsigned)dc * 1024u + ((unsigned)kp >> 3) * 8u + ((unsigned)kp & 1u) * 4u;

  #define STAGE_K(t, nb) { \
    _Pragma("unroll") \
    for (int j = 0; j < 4; ++j) { \
      const int c = wid * 4 + j; \
      const u16* gp = Kb + ((size_t)(t) * 32 + (c >> 3) * 16 + r16) * CDIM + (c & 7) * 32 + g * 8; \
      GLOAD16(gp, &Kf[nb][c * 512]); \
    } }

  #define LOAD_V(t, a0, a1, b0v, b1v) { \
    const u16* b0p = Vb + ((size_t)(t) * 32 + 2 * kp) * CDIM + dc * 16; \
    a0  = *(const short8*)(b0p);           a1  = *(const short8*)(b0p + 8); \
    b0v = *(const short8*)(b0p + CDIM);    b1v = *(const short8*)(b0p + CDIM + 8); \
  }

  #define WRITE_V(nb, a0, a1, b0v, b1v) { \
    _Pragma("unroll") \
    for (int u = 0; u < 16; ++u) { \
      u16 lo = (u < 8) ? (u16)a0[u] : (u16)a1[u - 8]; \
      u16 hi = (u < 8) ? (u16)b0v[u] : (u16)b1v[u - 8]; \
      unsigned w = (unsigned)lo | ((unsigned)hi << 16); \
      *(unsigned*)((char*)&Vf[nb][0] + wbase + ((gw * 16u + ((unsigned)u ^ mw)) * 16u)) = w; \
    } }

  {
    STAGE_K(s, 0);
    short8 a0, a1, b0v, b1v;
    LOAD_V(s, a0, a1, b0v, b1v);
    WRITE_V(0, a0, a1, b0v, b1v);
  }
  __syncthreads();

  int buf = 0;
  for (int t = s; t < NT; t += SPLIT, buf ^= 1) {
    const int tn = t + SPLIT, nb = buf ^ 1;
    short8 nva, nva1, nvb, nvb1;
    if (tn < NT) {
      STAGE_K(tn, nb);
      LOAD_V(tn, nva, nva1, nvb, nvb1);
    }
    f32x4 s0[2], s1[2];
    #pragma unroll
    for (int qs = 0; qs < 2; ++qs)
      #pragma unroll
      for (int r = 0; r < 4; ++r) { s0[qs][r] = 0.0f; s1[qs][r] = 0.0f; }
    __builtin_amdgcn_s_setprio(1);
    #pragma unroll
    for (int kc = 0; kc < 8; ++kc) {
      short8 k0 = *(const short8*)(&Kf[buf][kc * 512 + lane * 8]);
      short8 k1 = *(const short8*)(&Kf[buf][(8 + kc) * 512 + lane * 8]);
      s0[0] = mfma16(k0, qf[0][kc], s0[0]);
      s0[1] = mfma16(k0, qf[1][kc], s0[1]);
      s1[0] = mfma16(k1, qf[0][kc], s1[0]);
      s1[1] = mfma16(k1, qf[1][kc], s1[1]);
    }
    __builtin_amdgcn_s_setprio(0);
    short8 pbf[2];
    #pragma unroll
    for (int qs = 0; qs < 2; ++qs) {
      float p0[4], p1[4];
      #pragma unroll
      for (int r = 0; r < 4; ++r) {
        p0[r] = EXP2(s0[qs][r] - FM2);
        p1[r] = EXP2(s1[qs][r] - FM2);
        l_lane[qs] += p0[r] + p1[r];
      }
      pbf[qs] = pack8(p0[0], p0[1], p0[2], p0[3], p1[0], p1[1], p1[2], p1[3]);
    }
    __builtin_amdgcn_s_setprio(1);
    #pragma unroll
    for (int dt = 0; dt < 16; ++dt) {
      unsigned roff = (unsigned)dt * 1024u +
                      (((unsigned)lane ^ (((unsigned)g + 2u * (unsigned)dt) & 7u)) * 16u);
      short8 vv = *(const short8*)((const char*)&Vf[buf][0] + roff);
      oacc[0][dt] = mfma16(vv, pbf[0], oacc[0][dt]);
      oacc[1][dt] = mfma16(vv, pbf[1], oacc[1][dt]);
    }
    __builtin_amdgcn_s_setprio(0);
    if (tn < NT) WRITE_V(nb, nva, nva1, nvb, nvb1);
    __syncthreads();
  }

  #pragma unroll
  for (int qs = 0; qs < 2; ++qs) {
    l_lane[qs] += __shfl_xor(l_lane[qs], 16);
    l_lane[qs] += __shfl_xor(l_lane[qs], 32);
  }

  #pragma unroll
  for (int qs = 0; qs < 2; ++qs) {
    const size_t qrow = (size_t)qb * 128 + wid * 32 + qs * 16 + r16;
    const size_t obase = ((size_t)s * NQ + qrow) * CDIM;
    #pragma unroll
    for (int dt = 0; dt < 16; ++dt) {
      ushort4 o;
      o.x = f2b(oacc[qs][dt][0]); o.y = f2b(oacc[qs][dt][1]);
      o.z = f2b(oacc[qs][dt][2]); o.w = f2b(oacc[qs][dt][3]);
      *(ushort4*)(Opart + obase + dt * 16 + g * 4) = o;
    }
    if (lane < 16)
      lpart[(size_t)s * NQ + qb * 128 + wid * 32 + qs * 16 + lane] = l_lane[qs];
  }
}

// vectorized combine: block = 4 rows x 64 lanes; ushort4 loads per split.
__global__ __launch_bounds__(256)
void k_combine(const u16* __restrict__ Opart, const float* __restrict__ lpart,
               u16* __restrict__ out, int SPLIT) {
  int row = blockIdx.x * 4 + (threadIdx.x >> 6);
  int lane = threadIdx.x & 63;
  float L = 0.0f;
  float a0 = 0.0f, a1 = 0.0f, a2 = 0.0f, a3 = 0.0f;
  for (int s = 0; s < SPLIT; ++s) {
    L += lpart[(size_t)s * NQ + row];
    ushort4 v = *(const ushort4*)(Opart + ((size_t)s * NQ + row) * CDIM + lane * 4);
    a0 += b2f(v.x); a1 += b2f(v.y); a2 += b2f(v.z); a3 += b2f(v.w);
  }
  float rL = 1.0f / L;
  ushort4 o;
  o.x = f2b(a0 * rL); o.y = f2b(a1 * rL); o.z = f2b(a2 * rL); o.w = f2b(a3 * rL);
  *(ushort4*)(out + (size_t)row * CDIM + lane * 4) = o;
}

// ---------------- host ----------------

typedef void (*GemmFn)(const u16*, const u16*, const float*, const float*, void*, int, int, int, int);

extern "C" void kernel_launch(void* const* d_in, const int* in_sizes, int n_in,
                              void* d_out, int out_size, void* d_ws, size_t ws_size,
                              hipStream_t stream) {
  const float* image  = (const float*)d_in[0];
  const float* x      = (const float*)d_in[1];
  const float* mpos   = (const float*)d_in[4];
  const float* ropeT  = (const float*)d_in[5];
  const int*   nkx    = (const int*)d_in[6];
  const float QSCL = 0.0625f * 1.44269504089f;   // (1/sqrt(hd)) * log2(e)

  char* ws = (char*)d_ws;
  size_t off = 0;
  auto alloc = [&](size_t bytes) -> void* {
    void* p = ws + off;
    off += (bytes + 255) & ~(size_t)255;
    return p;
  };
  const size_t nq_c = (size_t)NQ * CDIM;
  const size_t nk_c = (size_t)NKTOT * CDIM;

  u16* w_sa_q = (u16*)alloc(65536 * 2);      // [sa_q; sa_k; sa_v] contiguous
  u16* w_sa_k = (u16*)alloc(65536 * 2);
  u16* w_sa_v = (u16*)alloc(65536 * 2);
  u16* w_sa_o = (u16*)alloc(65536 * 2);
  u16* w_ca_q = (u16*)alloc(65536 * 2);
  u16* w_ca_k = (u16*)alloc(65536 * 2);
  u16* w_ca_v = (u16*)alloc(65536 * 2);
  u16* w_ca_o = (u16*)alloc(65536 * 2);
  u16* w_ica_q = (u16*)alloc(65536 * 2);
  u16* w_ica_k = (u16*)alloc(65536 * 2);
  u16* w_l1 = (u16*)alloc(524288 * 2);
  u16* w_l2 = (u16*)alloc(524288 * 2);
  float* bqkv = (float*)alloc(768 * 4);
  u16* img16  = (u16*)alloc(nq_c * 2);
  // ---- region below hosts flash O-partials (33.5 MB) during both flash calls ----
  u16* mimg16 = (u16*)alloc(nk_c * 2);
  u16* mem16  = (u16*)alloc(nk_c * 2);
  u16* nbuf   = (u16*)alloc(nq_c * 2);
  float* ktmp = (float*)alloc(nk_c * 4);   // MLP hidden
  u16* qr16  = (u16*)alloc(nq_c * 2);
  u16* kr16  = (u16*)alloc(nq_c * 2);
  u16* v16   = (u16*)alloc(nq_c * 2);
  u16* k2r16 = (u16*)alloc(nk_c * 2);
  u16* v216  = (u16*)alloc(nk_c * 2);
  u16* ao16  = (u16*)alloc(nq_c * 2);
  float* x1  = (float*)alloc(nq_c * 4);
  float* x2  = (float*)alloc(nq_c * 4);
  float* lpart = (float*)alloc((size_t)FSPLIT * NQ * 4);
  u16* h16 = (u16*)ktmp;           // MLP hidden overlays ktmp
  u16* opart = (u16*)mimg16;       // flash O-partials (bf16) overlay mimg16..
  float* out_img = (float*)d_out;
  float* out_x   = (float*)d_out + nq_c;

  auto gemm = [&](GemmFn fn, const u16* A, const u16* W, const void* bias,
                  const float* cadd, void* out, int M, int N, int K, int lda) {
    fn<<<dim3(N / 64, M / 64), dim3(256), 0, stream>>>(A, W, (const float*)bias, cadd, out, M, N, K, lda);
  };

  // batched weight conversion (12 buffers, 1 dispatch) + image cvt+passthrough
  {
    CvtBatch cb;
    const int srcIdx[12] = {7, 9, 11, 13, 15, 17, 19, 21, 23, 25, 27, 29};
    u16* dsts[12] = {w_sa_q, w_sa_k, w_sa_v, w_sa_o, w_ca_q, w_ca_k,
                     w_ca_v, w_ca_o, w_ica_q, w_ica_k, w_l1, w_l2};
    for (int i = 0; i < 12; ++i) {
      cb.src[i] = (const float*)d_in[srcIdx[i]];
      cb.dst[i] = dsts[i];
      cb.n4[i] = (i < 10) ? 16384 : 131072;
    }
    k_f2b_batch<<<dim3(64, 12), dim3(256), 0, stream>>>(cb);
  }
  k_cvtcopy<<<dim3(1024), dim3(256), 0, stream>>>(image, img16, out_img, (int)(nq_c / 4));
  k_cat3<<<dim3(1), dim3(768), 0, stream>>>((const float*)d_in[8], (const float*)d_in[10],
                                            (const float*)d_in[12], bqkv);

  // ---- self-attention block ----
  k_ln<<<dim3(NQ / 4), dim3(256), 0, stream>>>(x, (const float*)d_in[31], (const float*)d_in[32], nbuf, NQ);
  k_gemm_qkv<<<dim3(768 / 64, NQ / 64), dim3(256), 0, stream>>>(
      nbuf, w_sa_q, bqkv, ropeT, qr16, kr16, v16, QSCL);
  k_flash<<<dim3(512), dim3(256), 0, stream>>>(qr16, kr16, v16, opart, lpart, NQ / 32, FSPLIT);
  k_combine<<<dim3(NQ / 4), dim3(256), 0, stream>>>(opart, lpart, ao16, FSPLIT);
  gemm(k_gemm<0,1,0,1>, ao16, w_sa_o, d_in[14], x, x1, NQ, CDIM, CDIM, CDIM);

  // ---- cross-attention block ----
  {
    CvtBatch cb;
    cb.src[0] = (const float*)d_in[2]; cb.dst[0] = mimg16; cb.n4[0] = (int)(nk_c / 4);
    cb.src[1] = (const float*)d_in[3]; cb.dst[1] = mem16;  cb.n4[1] = (int)(nk_c / 4);
    k_f2b_batch<<<dim3(512, 2), dim3(256), 0, stream>>>(cb);
  }
  k_ln<<<dim3(NQ / 4), dim3(256), 0, stream>>>(x1, (const float*)d_in[33], (const float*)d_in[34], nbuf, NQ);
  {
    GBatch gb;
    gb.op[0] = { img16, w_ica_q, nbuf, w_ca_q,
                 (const float*)d_in[24], (const float*)d_in[16], nullptr,
                 qr16, ropeT, nullptr, NQ, QSCL };
    gb.op[1] = { mimg16, w_ica_k, mem16, w_ca_k,
                 (const float*)d_in[26], (const float*)d_in[18], mpos,
                 k2r16, ropeT, nkx, NKTOT, 1.0f };
    gb.op[2] = { mem16, w_ca_v, nullptr, nullptr,
                 (const float*)d_in[20], nullptr, nullptr,
                 v216, nullptr, nullptr, 0, 1.0f };
    gb.start1 = (NQ / 64) * 4;                   // 256
    gb.start2 = gb.start1 + (NKTOT / 64) * 4;    // 1284
    int total = gb.start2 + (NKTOT / 64) * 4;    // 2312
    k_gemm_ca<<<dim3(total), dim3(256), 0, stream>>>(gb);
  }
  k_flash<<<dim3(512), dim3(256), 0, stream>>>(qr16, k2r16, v216, opart, lpart, NKTOT / 32, FSPLIT);
  k_combine<<<dim3(NQ / 4), dim3(256), 0, stream>>>(opart, lpart, ao16, FSPLIT);
  gemm(k_gemm<0,1,0,1>, ao16, w_ca_o, d_in[22], x1, x2, NQ, CDIM, CDIM, CDIM);

  // ---- MLP block ----
  k_ln<<<dim3(NQ / 4), dim3(256), 0, stream>>>(x2, (const float*)d_in[35], (const float*)d_in[36], nbuf, NQ);
  gemm(k_gemm<1,0,1,1>, nbuf, w_l1, d_in[28], nullptr, h16, NQ, FF, CDIM, CDIM);
  // l2 direct: out_x = h16 @ w_l2^T + bias + x2 (K=2048, one pass, no partials)
  gemm(k_gemm<0,1,0,1>, h16, w_l2, d_in[30], x2, out_x, NQ, CDIM, FF, FF);
}

// Round 20
// 321.836 us; speedup vs baseline: 1.0287x; 1.0287x over previous
//
#include <hip/hip_runtime.h>
#include <cstdint>

#define NQ 4096
#define NKTOT 16448
#define CDIM 256
#define FF 2048
#define FSPLIT 16

typedef unsigned short u16;
typedef __attribute__((ext_vector_type(8))) short short8;
typedef __attribute__((ext_vector_type(4))) float f32x4;

#define GLOAD16(gp, lp) __builtin_amdgcn_global_load_lds( \
    (const __attribute__((address_space(1))) unsigned int*)(gp), \
    (__attribute__((address_space(3))) unsigned int*)(lp), 16, 0, 0)

#if __has_builtin(__builtin_amdgcn_exp2f)
#define EXP2(x) __builtin_amdgcn_exp2f(x)
#else
#define EXP2(x) exp2f(x)
#endif

static __device__ __forceinline__ u16 f2b(float f) {
  union { float f; unsigned u; } v; v.f = f;
  unsigned r = v.u + 0x7fffu + ((v.u >> 16) & 1u);
  return (u16)(r >> 16);
}
static __device__ __forceinline__ float b2f(u16 h) {
  union { unsigned u; float f; } v; v.u = ((unsigned)h) << 16; return v.f;
}

// pack 8 f32 -> 8 bf16 via 4x v_cvt_pk_bf16_f32 (HW RTNE)
static __device__ __forceinline__ short8 pack8(float a0, float a1, float a2, float a3,
                                               float b0, float b1, float b2, float b3) {
  union { unsigned u[4]; short8 v; } r;
  asm("v_cvt_pk_bf16_f32 %0, %1, %2" : "=v"(r.u[0]) : "v"(a0), "v"(a1));
  asm("v_cvt_pk_bf16_f32 %0, %1, %2" : "=v"(r.u[1]) : "v"(a2), "v"(a3));
  asm("v_cvt_pk_bf16_f32 %0, %1, %2" : "=v"(r.u[2]) : "v"(b0), "v"(b1));
  asm("v_cvt_pk_bf16_f32 %0, %1, %2" : "=v"(r.u[3]) : "v"(b2), "v"(b3));
  return r.v;
}

static __device__ __forceinline__ f32x4 mfma16(short8 a, short8 b, f32x4 c) {
  return __builtin_amdgcn_mfma_f32_16x16x32_bf16(a, b, c, 0, 0, 0);
}

// ---------------- elementwise kernels ----------------

struct CvtBatch {
  const float* src[12];
  u16* dst[12];
  int n4[12];
};

__global__ void k_f2b_batch(CvtBatch cb) {
  int b = blockIdx.y;
  const float* in = cb.src[b];
  u16* out = cb.dst[b];
  int n4 = cb.n4[b];
  int stride = gridDim.x * blockDim.x;
  for (int i = blockIdx.x * blockDim.x + threadIdx.x; i < n4; i += stride) {
    float4 v = ((const float4*)in)[i];
    ushort4 o;
    o.x = f2b(v.x); o.y = f2b(v.y); o.z = f2b(v.z); o.w = f2b(v.w);
    ((ushort4*)out)[i] = o;
  }
}

// image: one read -> bf16 img16 + f32 passthrough out_img
__global__ void k_cvtcopy(const float* __restrict__ in, u16* __restrict__ ob,
                          float* __restrict__ of, int n4) {
  int stride = gridDim.x * blockDim.x;
  for (int i = blockIdx.x * blockDim.x + threadIdx.x; i < n4; i += stride) {
    float4 v = ((const float4*)in)[i];
    ushort4 o;
    o.x = f2b(v.x); o.y = f2b(v.y); o.z = f2b(v.z); o.w = f2b(v.w);
    ((ushort4*)ob)[i] = o;
    ((float4*)of)[i] = v;
  }
}

__global__ void k_cat3(const float* __restrict__ a, const float* __restrict__ b,
                       const float* __restrict__ c, float* __restrict__ o) {
  int i = threadIdx.x;
  o[i] = (i < 256) ? a[i] : ((i < 512) ? b[i - 256] : c[i - 512]);
}

__global__ void k_addmix(const float4* __restrict__ P0, const float4* __restrict__ P1,
                         const float* __restrict__ bias, const float4* __restrict__ xres,
                         float4* __restrict__ out, int n4) {
  int i = blockIdx.x * blockDim.x + threadIdx.x;
  if (i >= n4) return;
  int c4 = (i & 63) * 4;
  float4 a = P0[i], b = P1[i], c = xres[i];
  float4 o;
  o.x = a.x + b.x + bias[c4]     + c.x;
  o.y = a.y + b.y + bias[c4 + 1] + c.y;
  o.z = a.z + b.z + bias[c4 + 2] + c.z;
  o.w = a.w + b.w + bias[c4 + 3] + c.w;
  out[i] = o;
}

__global__ __launch_bounds__(256)
void k_ln(const float* __restrict__ x, const float* __restrict__ w,
          const float* __restrict__ b, u16* __restrict__ out, int M) {
  int row = blockIdx.x * 4 + (threadIdx.x >> 6);
  int lane = threadIdx.x & 63;
  const float4 v = ((const float4*)(x + (size_t)row * CDIM))[lane];
  float s = v.x + v.y + v.z + v.w;
  float s2 = v.x * v.x + v.y * v.y + v.z * v.z + v.w * v.w;
  #pragma unroll
  for (int d = 1; d < 64; d <<= 1) { s += __shfl_xor(s, d); s2 += __shfl_xor(s2, d); }
  float mean = s * (1.0f / CDIM);
  float rstd = rsqrtf(s2 * (1.0f / CDIM) - mean * mean + 1e-5f);
  float4 wv = ((const float4*)w)[lane];
  float4 bv = ((const float4*)b)[lane];
  ushort4 o;
  o.x = f2b((v.x - mean) * rstd * wv.x + bv.x);
  o.y = f2b((v.y - mean) * rstd * wv.y + bv.y);
  o.z = f2b((v.z - mean) * rstd * wv.z + bv.z);
  o.w = f2b((v.w - mean) * rstd * wv.w + bv.w);
  ((ushort4*)(out + (size_t)row * CDIM))[lane] = o;
}

// ---------------- GEMM: 64x64 tile, BK=64, fragment-order DMA, double-buffered ----

template<int GELU, int HASADD, int OUTBF, int HASBIAS>
__global__ __launch_bounds__(256)
void k_gemm(const u16* __restrict__ A, const u16* __restrict__ W,
            const float* __restrict__ bias, const float* __restrict__ Cadd,
            void* __restrict__ outp, int M, int N, int K, int lda) {
  __shared__ u16 Sg[2][2][4096];
  const int bm = blockIdx.y * 64, bn = blockIdx.x * 64;
  const int tid = threadIdx.x;
  const int lane = tid & 63, wid = tid >> 6;
  const int r16 = lane & 15, g = lane >> 4;
  const int wm = (wid >> 1) * 32, wn = (wid & 1) * 32;
  f32x4 acc[2][2];
  #pragma unroll
  for (int i = 0; i < 2; ++i)
    #pragma unroll
    for (int j = 0; j < 2; ++j)
      #pragma unroll
      for (int r = 0; r < 4; ++r) acc[i][j][r] = 0.0f;
  const int ca0 = (wid >> 1) * 4, cb0 = (wid & 1) * 4;

  #define GSTAGE(k0s, nb) { \
    _Pragma("unroll") \
    for (int j = 0; j < 4; ++j) { \
      const int c = wid * 4 + j; \
      const int cc = c & 7; \
      const u16* base = (c < 8) ? A : W; \
      const int row = ((c < 8) ? bm : bn) + (cc >> 1) * 16 + r16; \
      const int col = (k0s) + (cc & 1) * 32 + g * 8; \
      GLOAD16(base + (size_t)row * lda + col, &Sg[nb][c >> 3][cc * 512]); \
    } }

  GSTAGE(0, 0);
  __syncthreads();
  int buf = 0;
  for (int k0 = 0; k0 < K; k0 += 64, buf ^= 1) {
    if (k0 + 64 < K) GSTAGE(k0 + 64, buf ^ 1);
    #pragma unroll
    for (int kc = 0; kc < 2; ++kc) {
      short8 a0 = *(const short8*)(&Sg[buf][0][(ca0 + kc) * 512 + lane * 8]);
      short8 a1 = *(const short8*)(&Sg[buf][0][(ca0 + 2 + kc) * 512 + lane * 8]);
      short8 b0 = *(const short8*)(&Sg[buf][1][(cb0 + kc) * 512 + lane * 8]);
      short8 b1 = *(const short8*)(&Sg[buf][1][(cb0 + 2 + kc) * 512 + lane * 8]);
      acc[0][0] = mfma16(a0, b0, acc[0][0]);
      acc[0][1] = mfma16(a0, b1, acc[0][1]);
      acc[1][0] = mfma16(a1, b0, acc[1][0]);
      acc[1][1] = mfma16(a1, b1, acc[1][1]);
    }
    __syncthreads();
  }
  #pragma unroll
  for (int tr = 0; tr < 2; ++tr)
    #pragma unroll
    for (int tc = 0; tc < 2; ++tc)
      #pragma unroll
      for (int r = 0; r < 4; ++r) {
        int row = bm + wm + tr * 16 + g * 4 + r;
        int col = bn + wn + tc * 16 + r16;
        float v = acc[tr][tc][r];
        if (HASBIAS) v += bias[col];
        if (HASADD) v += Cadd[(size_t)row * N + col];
        if (GELU) v = 0.5f * v * (1.0f + erff(v * 0.70710678118654752f));
        if (OUTBF) ((u16*)outp)[(size_t)row * N + col] = f2b(v);
        else ((float*)outp)[(size_t)row * N + col] = v;
      }
}

// fused SA qkv GEMM: N=768, K=256 (64x64 tile). Epilogue: rope/scale/convert.
__global__ __launch_bounds__(256)
void k_gemm_qkv(const u16* __restrict__ A, const u16* __restrict__ W,
                const float* __restrict__ bias, const float* __restrict__ freqs,
                u16* __restrict__ qr, u16* __restrict__ kr, u16* __restrict__ vb,
                float qscl) {
  __shared__ u16 Sg[2][2][4096];
  const int bm = blockIdx.y * 64, bn = blockIdx.x * 64;
  const int tid = threadIdx.x;
  const int lane = tid & 63, wid = tid >> 6;
  const int r16 = lane & 15, g = lane >> 4;
  const int wm = (wid >> 1) * 32, wn = (wid & 1) * 32;
  const int lda = 256;
  const u16* Wb = W;
  #define AW(c) ((c) < 8 ? A : Wb)
  f32x4 acc[2][2];
  #pragma unroll
  for (int i = 0; i < 2; ++i)
    #pragma unroll
    for (int j = 0; j < 2; ++j)
      #pragma unroll
      for (int r = 0; r < 4; ++r) acc[i][j][r] = 0.0f;
  const int ca0 = (wid >> 1) * 4, cb0 = (wid & 1) * 4;

  #define GSTAGEQ(k0s, nb) { \
    _Pragma("unroll") \
    for (int j = 0; j < 4; ++j) { \
      const int c = wid * 4 + j; \
      const int cc = c & 7; \
      const u16* base = AW(c); \
      const int row = ((c < 8) ? bm : bn) + (cc >> 1) * 16 + r16; \
      const int col = (k0s) + (cc & 1) * 32 + g * 8; \
      GLOAD16(base + (size_t)row * lda + col, &Sg[nb][c >> 3][cc * 512]); \
    } }

  GSTAGEQ(0, 0);
  __syncthreads();
  int buf = 0;
  for (int k0 = 0; k0 < 256; k0 += 64, buf ^= 1) {
    if (k0 + 64 < 256) GSTAGEQ(k0 + 64, buf ^ 1);
    #pragma unroll
    for (int kc = 0; kc < 2; ++kc) {
      short8 a0 = *(const short8*)(&Sg[buf][0][(ca0 + kc) * 512 + lane * 8]);
      short8 a1 = *(const short8*)(&Sg[buf][0][(ca0 + 2 + kc) * 512 + lane * 8]);
      short8 b0 = *(const short8*)(&Sg[buf][1][(cb0 + kc) * 512 + lane * 8]);
      short8 b1 = *(const short8*)(&Sg[buf][1][(cb0 + 2 + kc) * 512 + lane * 8]);
      acc[0][0] = mfma16(a0, b0, acc[0][0]);
      acc[0][1] = mfma16(a0, b1, acc[0][1]);
      acc[1][0] = mfma16(a1, b0, acc[1][0]);
      acc[1][1] = mfma16(a1, b1, acc[1][1]);
    }
    __syncthreads();
  }
  #pragma unroll
  for (int tr = 0; tr < 2; ++tr)
    #pragma unroll
    for (int tc = 0; tc < 2; ++tc)
      #pragma unroll
      for (int r = 0; r < 4; ++r) {
        int row = bm + wm + tr * 16 + g * 4 + r;
        int col = bn + wn + tc * 16 + r16;
        float v = acc[tr][tc][r] + bias[col];
        int sec = col >> 8;         // 0=q 1=k 2=v
        int c = col & 255;
        float vp = __shfl_xor(v, 1);
        if (sec < 2) {
          float4 f = ((const float4*)freqs)[(size_t)row * 128 + (c >> 1)];
          v = (c & 1) ? (f.z * vp + f.w * v) : (f.x * v + f.y * vp);
          if (sec == 0) v *= qscl;
        }
        u16* ob = (sec == 0) ? qr : ((sec == 1) ? kr : vb);
        ob[(size_t)row * 256 + c] = f2b(v);
      }
}

// split-K (2-way) GEMM over K=2048 (64x64 tile): z picks half; f32 out, no bias.
__global__ __launch_bounds__(256)
void k_gemm_sk(const u16* __restrict__ A0, const u16* __restrict__ W0,
               float* __restrict__ out0, float* __restrict__ out1, int M, int N) {
  __shared__ u16 Sg[2][2][4096];
  const int z = blockIdx.z;
  const u16* A = A0 + z * 1024;
  const u16* W = W0 + z * 1024;
  float* outp = z ? out1 : out0;
  const int lda = 2048, K = 1024;
  const int bm = blockIdx.y * 64, bn = blockIdx.x * 64;
  const int tid = threadIdx.x;
  const int lane = tid & 63, wid = tid >> 6;
  const int r16 = lane & 15, g = lane >> 4;
  const int wm = (wid >> 1) * 32, wn = (wid & 1) * 32;
  f32x4 acc[2][2];
  #pragma unroll
  for (int i = 0; i < 2; ++i)
    #pragma unroll
    for (int j = 0; j < 2; ++j)
      #pragma unroll
      for (int r = 0; r < 4; ++r) acc[i][j][r] = 0.0f;
  const int ca0 = (wid >> 1) * 4, cb0 = (wid & 1) * 4;
  GSTAGE(0, 0);
  __syncthreads();
  int buf = 0;
  for (int k0 = 0; k0 < K; k0 += 64, buf ^= 1) {
    if (k0 + 64 < K) GSTAGE(k0 + 64, buf ^ 1);
    #pragma unroll
    for (int kc = 0; kc < 2; ++kc) {
      short8 a0 = *(const short8*)(&Sg[buf][0][(ca0 + kc) * 512 + lane * 8]);
      short8 a1 = *(const short8*)(&Sg[buf][0][(ca0 + 2 + kc) * 512 + lane * 8]);
      short8 b0 = *(const short8*)(&Sg[buf][1][(cb0 + kc) * 512 + lane * 8]);
      short8 b1 = *(const short8*)(&Sg[buf][1][(cb0 + 2 + kc) * 512 + lane * 8]);
      acc[0][0] = mfma16(a0, b0, acc[0][0]);
      acc[0][1] = mfma16(a0, b1, acc[0][1]);
      acc[1][0] = mfma16(a1, b0, acc[1][0]);
      acc[1][1] = mfma16(a1, b1, acc[1][1]);
    }
    __syncthreads();
  }
  #pragma unroll
  for (int tr = 0; tr < 2; ++tr)
    #pragma unroll
    for (int tc = 0; tc < 2; ++tc)
      #pragma unroll
      for (int r = 0; r < 4; ++r) {
        int row = bm + wm + tr * 16 + g * 4 + r;
        int col = bn + wn + tc * 16 + r16;
        outp[(size_t)row * N + col] = acc[tr][tc][r];
      }
}

// ---- batched CA GEMMs: 3 independent N=256 ops in one dispatch, fused rope ----
struct GOp {
  const u16 *A1, *W1, *A2, *W2;
  const float *b1, *b2, *cadd;
  u16* out;
  const float* freqs;   // null = no rope
  const int* nkxp;
  int limit_base;
  float scale;
};
struct GBatch { GOp op[3]; int start1, start2; };

__global__ __launch_bounds__(256)
void k_gemm_ca(GBatch gb) {
  __shared__ u16 Sg[2][2][4096];
  const int flat = blockIdx.x;
  const int oi = (flat >= gb.start1) + (flat >= gb.start2);
  const int local = flat - (oi == 0 ? 0 : (oi == 1 ? gb.start1 : gb.start2));
  const GOp op = gb.op[oi];
  const int bn = (local & 3) * 64;
  const int bm = (local >> 2) * 64;
  const int K = op.A2 ? 512 : 256;
  const int tid = threadIdx.x;
  const int lane = tid & 63, wid = tid >> 6;
  const int r16 = lane & 15, g = lane >> 4;
  const int wm = (wid >> 1) * 32, wn = (wid & 1) * 32;
  f32x4 acc[2][2];
  #pragma unroll
  for (int i = 0; i < 2; ++i)
    #pragma unroll
    for (int j = 0; j < 2; ++j)
      #pragma unroll
      for (int r = 0; r < 4; ++r) acc[i][j][r] = 0.0f;
  const int ca0 = (wid >> 1) * 4, cb0 = (wid & 1) * 4;

  #define GSTAGE_CA(k0s, nb) { \
    const u16* As = ((k0s) < 256) ? op.A1 : op.A2; \
    const u16* Ws = ((k0s) < 256) ? op.W1 : op.W2; \
    const int kk = (k0s) & 255; \
    _Pragma("unroll") \
    for (int j = 0; j < 4; ++j) { \
      const int c = wid * 4 + j; \
      const int cc = c & 7; \
      const u16* base = (c < 8) ? As : Ws; \
      const int row = ((c < 8) ? bm : bn) + (cc >> 1) * 16 + r16; \
      const int col = kk + (cc & 1) * 32 + g * 8; \
      GLOAD16(base + (size_t)row * 256 + col, &Sg[nb][c >> 3][cc * 512]); \
    } }

  GSTAGE_CA(0, 0);
  __syncthreads();
  int buf = 0;
  for (int k0 = 0; k0 < K; k0 += 64, buf ^= 1) {
    if (k0 + 64 < K) GSTAGE_CA(k0 + 64, buf ^ 1);
    #pragma unroll
    for (int kc = 0; kc < 2; ++kc) {
      short8 a0 = *(const short8*)(&Sg[buf][0][(ca0 + kc) * 512 + lane * 8]);
      short8 a1 = *(const short8*)(&Sg[buf][0][(ca0 + 2 + kc) * 512 + lane * 8]);
      short8 b0 = *(const short8*)(&Sg[buf][1][(cb0 + kc) * 512 + lane * 8]);
      short8 b1 = *(const short8*)(&Sg[buf][1][(cb0 + 2 + kc) * 512 + lane * 8]);
      acc[0][0] = mfma16(a0, b0, acc[0][0]);
      acc[0][1] = mfma16(a0, b1, acc[0][1]);
      acc[1][0] = mfma16(a1, b0, acc[1][0]);
      acc[1][1] = mfma16(a1, b1, acc[1][1]);
    }
    __syncthreads();
  }
  const int lim = op.limit_base - (op.nkxp ? *op.nkxp : 0);
  #pragma unroll
  for (int tr = 0; tr < 2; ++tr)
    #pragma unroll
    for (int tc = 0; tc < 2; ++tc)
      #pragma unroll
      for (int r = 0; r < 4; ++r) {
        int row = bm + wm + tr * 16 + g * 4 + r;
        int col = bn + wn + tc * 16 + r16;
        float v = acc[tr][tc][r] + op.b1[col];
        if (op.b2) v += op.b2[col];
        if (op.cadd) v += op.cadd[(size_t)row * 256 + col];
        if (op.freqs) {
          float vp = __shfl_xor(v, 1);
          if (row < lim) {
            float4 f = ((const float4*)op.freqs)[((size_t)(row & 4095)) * 128 + (col >> 1)];
            v = (col & 1) ? (f.z * vp + f.w * v) : (f.x * v + f.y * vp);
          }
          v *= op.scale;
        }
        op.out[(size_t)row * 256 + col] = f2b(v);
      }
}

// ---------------- flash attention (1 head, hd=256), KV-split partials ----------------
// 1D grid 512 with XCD-aware decode: s = (flat&7) + 8*(flat>>8), qb = (flat>>3)&31.
// All 32 q-blocks sharing a KV-split s land on one XCD -> s-slice of K/V stays
// L2-resident (FETCH 69.7 -> 19 MB measured). block 256 = 4 waves; wave owns
// 32 q-rows (2 subtiles); KV tile = 32 keys. Swapped QK^T natural key order;
// P packs into K=32 B-frag; PV = 1 mfma16 per dim-tile per q-subtile.
// K and V double-buffered, ONE barrier per tile.

#define FM2 23.0831206542f   // 16 * log2(e)

__global__ __launch_bounds__(256, 2)
void k_flash(const u16* __restrict__ Q, const u16* __restrict__ Kb, const u16* __restrict__ Vb,
             u16* __restrict__ Opart, float* __restrict__ lpart, int NT, int SPLIT) {
  __shared__ u16 Kf[2][8192];
  __shared__ u16 Vf[2][8192];
  const int flat = blockIdx.x;
  const int s = (flat & 7) + 8 * (flat >> 8);
  const int qb = (flat >> 3) & 31;
  const int tid = threadIdx.x, lane = tid & 63, wid = tid >> 6;
  const int r16 = lane & 15, g = lane >> 4;

  short8 qf[2][8];
  #pragma unroll
  for (int qs = 0; qs < 2; ++qs) {
    const size_t qrow = (size_t)qb * 128 + wid * 32 + qs * 16 + r16;
    #pragma unroll
    for (int kc = 0; kc < 8; ++kc)
      qf[qs][kc] = *(const short8*)(Q + qrow * CDIM + kc * 32 + g * 8);
  }

  float l_lane[2] = {0.0f, 0.0f};
  f32x4 oacc[2][16];
  #pragma unroll
  for (int qs = 0; qs < 2; ++qs)
    #pragma unroll
    for (int i = 0; i < 16; ++i)
      #pragma unroll
      for (int r = 0; r < 4; ++r) oacc[qs][i][r] = 0.0f;

  const int kp = tid & 15, dc = tid >> 4;
  const unsigned gw = ((unsigned)kp & 7u) >> 1;
  const unsigned mw = (gw + 2u * (unsigned)dc) & 7u;
  const unsigned wbase = (unsigned)dc * 1024u + ((unsigned)kp >> 3) * 8u + ((unsigned)kp & 1u) * 4u;

  #define STAGE_K(t, nb) { \
    _Pragma("unroll") \
    for (int j = 0; j < 4; ++j) { \
      const int c = wid * 4 + j; \
      const u16* gp = Kb + ((size_t)(t) * 32 + (c >> 3) * 16 + r16) * CDIM + (c & 7) * 32 + g * 8; \
      GLOAD16(gp, &Kf[nb][c * 512]); \
    } }

  #define LOAD_V(t, a0, a1, b0v, b1v) { \
    const u16* b0p = Vb + ((size_t)(t) * 32 + 2 * kp) * CDIM + dc * 16; \
    a0  = *(const short8*)(b0p);           a1  = *(const short8*)(b0p + 8); \
    b0v = *(const short8*)(b0p + CDIM);    b1v = *(const short8*)(b0p + CDIM + 8); \
  }

  #define WRITE_V(nb, a0, a1, b0v, b1v) { \
    _Pragma("unroll") \
    for (int u = 0; u < 16; ++u) { \
      u16 lo = (u < 8) ? (u16)a0[u] : (u16)a1[u - 8]; \
      u16 hi = (u < 8) ? (u16)b0v[u] : (u16)b1v[u - 8]; \
      unsigned w = (unsigned)lo | ((unsigned)hi << 16); \
      *(unsigned*)((char*)&Vf[nb][0] + wbase + ((gw * 16u + ((unsigned)u ^ mw)) * 16u)) = w; \
    } }

  {
    STAGE_K(s, 0);
    short8 a0, a1, b0v, b1v;
    LOAD_V(s, a0, a1, b0v, b1v);
    WRITE_V(0, a0, a1, b0v, b1v);
  }
  __syncthreads();

  int buf = 0;
  for (int t = s; t < NT; t += SPLIT, buf ^= 1) {
    const int tn = t + SPLIT, nb = buf ^ 1;
    short8 nva, nva1, nvb, nvb1;
    if (tn < NT) {
      STAGE_K(tn, nb);
      LOAD_V(tn, nva, nva1, nvb, nvb1);
    }
    f32x4 s0[2], s1[2];
    #pragma unroll
    for (int qs = 0; qs < 2; ++qs)
      #pragma unroll
      for (int r = 0; r < 4; ++r) { s0[qs][r] = 0.0f; s1[qs][r] = 0.0f; }
    __builtin_amdgcn_s_setprio(1);
    #pragma unroll
    for (int kc = 0; kc < 8; ++kc) {
      short8 k0 = *(const short8*)(&Kf[buf][kc * 512 + lane * 8]);
      short8 k1 = *(const short8*)(&Kf[buf][(8 + kc) * 512 + lane * 8]);
      s0[0] = mfma16(k0, qf[0][kc], s0[0]);
      s0[1] = mfma16(k0, qf[1][kc], s0[1]);
      s1[0] = mfma16(k1, qf[0][kc], s1[0]);
      s1[1] = mfma16(k1, qf[1][kc], s1[1]);
    }
    __builtin_amdgcn_s_setprio(0);
    short8 pbf[2];
    #pragma unroll
    for (int qs = 0; qs < 2; ++qs) {
      float p0[4], p1[4];
      #pragma unroll
      for (int r = 0; r < 4; ++r) {
        p0[r] = EXP2(s0[qs][r] - FM2);
        p1[r] = EXP2(s1[qs][r] - FM2);
        l_lane[qs] += p0[r] + p1[r];
      }
      pbf[qs] = pack8(p0[0], p0[1], p0[2], p0[3], p1[0], p1[1], p1[2], p1[3]);
    }
    __builtin_amdgcn_s_setprio(1);
    #pragma unroll
    for (int dt = 0; dt < 16; ++dt) {
      unsigned roff = (unsigned)dt * 1024u +
                      (((unsigned)lane ^ (((unsigned)g + 2u * (unsigned)dt) & 7u)) * 16u);
      short8 vv = *(const short8*)((const char*)&Vf[buf][0] + roff);
      oacc[0][dt] = mfma16(vv, pbf[0], oacc[0][dt]);
      oacc[1][dt] = mfma16(vv, pbf[1], oacc[1][dt]);
    }
    __builtin_amdgcn_s_setprio(0);
    if (tn < NT) WRITE_V(nb, nva, nva1, nvb, nvb1);
    __syncthreads();
  }

  #pragma unroll
  for (int qs = 0; qs < 2; ++qs) {
    l_lane[qs] += __shfl_xor(l_lane[qs], 16);
    l_lane[qs] += __shfl_xor(l_lane[qs], 32);
  }

  #pragma unroll
  for (int qs = 0; qs < 2; ++qs) {
    const size_t qrow = (size_t)qb * 128 + wid * 32 + qs * 16 + r16;
    const size_t obase = ((size_t)s * NQ + qrow) * CDIM;
    #pragma unroll
    for (int dt = 0; dt < 16; ++dt) {
      ushort4 o;
      o.x = f2b(oacc[qs][dt][0]); o.y = f2b(oacc[qs][dt][1]);
      o.z = f2b(oacc[qs][dt][2]); o.w = f2b(oacc[qs][dt][3]);
      *(ushort4*)(Opart + obase + dt * 16 + g * 4) = o;
    }
    if (lane < 16)
      lpart[(size_t)s * NQ + qb * 128 + wid * 32 + qs * 16 + lane] = l_lane[qs];
  }
}

// vectorized combine: block = 4 rows x 64 lanes; ushort4 loads per split.
__global__ __launch_bounds__(256)
void k_combine(const u16* __restrict__ Opart, const float* __restrict__ lpart,
               u16* __restrict__ out, int SPLIT) {
  int row = blockIdx.x * 4 + (threadIdx.x >> 6);
  int lane = threadIdx.x & 63;
  float L = 0.0f;
  float a0 = 0.0f, a1 = 0.0f, a2 = 0.0f, a3 = 0.0f;
  for (int s = 0; s < SPLIT; ++s) {
    L += lpart[(size_t)s * NQ + row];
    ushort4 v = *(const ushort4*)(Opart + ((size_t)s * NQ + row) * CDIM + lane * 4);
    a0 += b2f(v.x); a1 += b2f(v.y); a2 += b2f(v.z); a3 += b2f(v.w);
  }
  float rL = 1.0f / L;
  ushort4 o;
  o.x = f2b(a0 * rL); o.y = f2b(a1 * rL); o.z = f2b(a2 * rL); o.w = f2b(a3 * rL);
  *(ushort4*)(out + (size_t)row * CDIM + lane * 4) = o;
}

// ---------------- host ----------------

typedef void (*GemmFn)(const u16*, const u16*, const float*, const float*, void*, int, int, int, int);

extern "C" void kernel_launch(void* const* d_in, const int* in_sizes, int n_in,
                              void* d_out, int out_size, void* d_ws, size_t ws_size,
                              hipStream_t stream) {
  const float* image  = (const float*)d_in[0];
  const float* x      = (const float*)d_in[1];
  const float* mpos   = (const float*)d_in[4];
  const float* ropeT  = (const float*)d_in[5];
  const int*   nkx    = (const int*)d_in[6];
  const float QSCL = 0.0625f * 1.44269504089f;   // (1/sqrt(hd)) * log2(e)

  char* ws = (char*)d_ws;
  size_t off = 0;
  auto alloc = [&](size_t bytes) -> void* {
    void* p = ws + off;
    off += (bytes + 255) & ~(size_t)255;
    return p;
  };
  const size_t nq_c = (size_t)NQ * CDIM;
  const size_t nk_c = (size_t)NKTOT * CDIM;

  u16* w_sa_q = (u16*)alloc(65536 * 2);      // [sa_q; sa_k; sa_v] contiguous
  u16* w_sa_k = (u16*)alloc(65536 * 2);
  u16* w_sa_v = (u16*)alloc(65536 * 2);
  u16* w_sa_o = (u16*)alloc(65536 * 2);
  u16* w_ca_q = (u16*)alloc(65536 * 2);
  u16* w_ca_k = (u16*)alloc(65536 * 2);
  u16* w_ca_v = (u16*)alloc(65536 * 2);
  u16* w_ca_o = (u16*)alloc(65536 * 2);
  u16* w_ica_q = (u16*)alloc(65536 * 2);
  u16* w_ica_k = (u16*)alloc(65536 * 2);
  u16* w_l1 = (u16*)alloc(524288 * 2);
  u16* w_l2 = (u16*)alloc(524288 * 2);
  float* bqkv = (float*)alloc(768 * 4);
  u16* img16  = (u16*)alloc(nq_c * 2);
  // ---- region below hosts flash O-partials (33.5 MB) during both flash calls ----
  u16* mimg16 = (u16*)alloc(nk_c * 2);
  u16* mem16  = (u16*)alloc(nk_c * 2);
  u16* nbuf   = (u16*)alloc(nq_c * 2);
  float* qf   = (float*)alloc(nq_c * 4);   // l2 split-K partial P0
  float* kf   = (float*)alloc(nq_c * 4);   // l2 split-K partial P1
  float* ktmp = (float*)alloc(nk_c * 4);   // MLP hidden
  u16* qr16  = (u16*)alloc(nq_c * 2);
  u16* kr16  = (u16*)alloc(nq_c * 2);
  u16* v16   = (u16*)alloc(nq_c * 2);
  u16* k2r16 = (u16*)alloc(nk_c * 2);
  u16* v216  = (u16*)alloc(nk_c * 2);
  u16* ao16  = (u16*)alloc(nq_c * 2);
  float* x1  = (float*)alloc(nq_c * 4);
  float* x2  = (float*)alloc(nq_c * 4);
  float* lpart = (float*)alloc((size_t)FSPLIT * NQ * 4);
  u16* h16 = (u16*)ktmp;           // MLP hidden overlays ktmp
  u16* opart = (u16*)mimg16;       // flash O-partials (bf16) overlay mimg16..
  float* out_img = (float*)d_out;
  float* out_x   = (float*)d_out + nq_c;

  auto gemm = [&](GemmFn fn, const u16* A, const u16* W, const void* bias,
                  const float* cadd, void* out, int M, int N, int K, int lda) {
    fn<<<dim3(N / 64, M / 64), dim3(256), 0, stream>>>(A, W, (const float*)bias, cadd, out, M, N, K, lda);
  };

  // batched weight conversion (12 buffers, 1 dispatch) + image cvt+passthrough
  {
    CvtBatch cb;
    const int srcIdx[12] = {7, 9, 11, 13, 15, 17, 19, 21, 23, 25, 27, 29};
    u16* dsts[12] = {w_sa_q, w_sa_k, w_sa_v, w_sa_o, w_ca_q, w_ca_k,
                     w_ca_v, w_ca_o, w_ica_q, w_ica_k, w_l1, w_l2};
    for (int i = 0; i < 12; ++i) {
      cb.src[i] = (const float*)d_in[srcIdx[i]];
      cb.dst[i] = dsts[i];
      cb.n4[i] = (i < 10) ? 16384 : 131072;
    }
    k_f2b_batch<<<dim3(64, 12), dim3(256), 0, stream>>>(cb);
  }
  k_cvtcopy<<<dim3(1024), dim3(256), 0, stream>>>(image, img16, out_img, (int)(nq_c / 4));
  k_cat3<<<dim3(1), dim3(768), 0, stream>>>((const float*)d_in[8], (const float*)d_in[10],
                                            (const float*)d_in[12], bqkv);

  // ---- self-attention block ----
  k_ln<<<dim3(NQ / 4), dim3(256), 0, stream>>>(x, (const float*)d_in[31], (const float*)d_in[32], nbuf, NQ);
  k_gemm_qkv<<<dim3(768 / 64, NQ / 64), dim3(256), 0, stream>>>(
      nbuf, w_sa_q, bqkv, ropeT, qr16, kr16, v16, QSCL);
  k_flash<<<dim3(512), dim3(256), 0, stream>>>(qr16, kr16, v16, opart, lpart, NQ / 32, FSPLIT);
  k_combine<<<dim3(NQ / 4), dim3(256), 0, stream>>>(opart, lpart, ao16, FSPLIT);
  gemm(k_gemm<0,1,0,1>, ao16, w_sa_o, d_in[14], x, x1, NQ, CDIM, CDIM, CDIM);

  // ---- cross-attention block ----
  {
    CvtBatch cb;
    cb.src[0] = (const float*)d_in[2]; cb.dst[0] = mimg16; cb.n4[0] = (int)(nk_c / 4);
    cb.src[1] = (const float*)d_in[3]; cb.dst[1] = mem16;  cb.n4[1] = (int)(nk_c / 4);
    k_f2b_batch<<<dim3(512, 2), dim3(256), 0, stream>>>(cb);
  }
  k_ln<<<dim3(NQ / 4), dim3(256), 0, stream>>>(x1, (const float*)d_in[33], (const float*)d_in[34], nbuf, NQ);
  {
    GBatch gb;
    gb.op[0] = { img16, w_ica_q, nbuf, w_ca_q,
                 (const float*)d_in[24], (const float*)d_in[16], nullptr,
                 qr16, ropeT, nullptr, NQ, QSCL };
    gb.op[1] = { mimg16, w_ica_k, mem16, w_ca_k,
                 (const float*)d_in[26], (const float*)d_in[18], mpos,
                 k2r16, ropeT, nkx, NKTOT, 1.0f };
    gb.op[2] = { mem16, w_ca_v, nullptr, nullptr,
                 (const float*)d_in[20], nullptr, nullptr,
                 v216, nullptr, nullptr, 0, 1.0f };
    gb.start1 = (NQ / 64) * 4;                   // 256
    gb.start2 = gb.start1 + (NKTOT / 64) * 4;    // 1284
    int total = gb.start2 + (NKTOT / 64) * 4;    // 2312
    k_gemm_ca<<<dim3(total), dim3(256), 0, stream>>>(gb);
  }
  k_flash<<<dim3(512), dim3(256), 0, stream>>>(qr16, k2r16, v216, opart, lpart, NKTOT / 32, FSPLIT);
  k_combine<<<dim3(NQ / 4), dim3(256), 0, stream>>>(opart, lpart, ao16, FSPLIT);
  gemm(k_gemm<0,1,0,1>, ao16, w_ca_o, d_in[22], x1, x2, NQ, CDIM, CDIM, CDIM);

  // ---- MLP block ----
  k_ln<<<dim3(NQ / 4), dim3(256), 0, stream>>>(x2, (const float*)d_in[35], (const float*)d_in[36], nbuf, NQ);
  gemm(k_gemm<1,0,1,1>, nbuf, w_l1, d_in[28], nullptr, h16, NQ, FF, CDIM, CDIM);
  k_gemm_sk<<<dim3(CDIM / 64, NQ / 64, 2), dim3(256), 0, stream>>>(h16, w_l2, qf, kf, NQ, CDIM);
  k_addmix<<<dim3((int)(nq_c / 4 + 255) / 256), dim3(256), 0, stream>>>(
      (const float4*)qf, (const float4*)kf, (const float*)d_in[30],
      (const float4*)x2, (float4*)out_x, (int)(nq_c / 4));
}